// Round 16
// baseline (54.674 us; speedup 1.0000x reference)
//
#include <hip/hip_runtime.h>

typedef unsigned long long u64;

#define NPTS 8192
#define DIM  512
#define NK   64
#define BM   128            // rows per tile
#define KP   16             // K-split parts
#define KD   32             // dims per part
#define NT   (NPTS/BM)      // 64 tiles
#define ALP  132            // Al pitch (floats): 128 rows + 4 pad (== 4 mod 32)
#define BLP  68             // Bl pitch (floats): 64 cols + 4 pad

// workspace layout (float offsets)
#define WS_DOT  0                       // [KP*NK][NPTS] = 33.6 MB
#define WS_STAT (KP * NK * NPTS)        // [KP][NPTS] float2 = 1 MB

// ---------------------------------------------------------------------------
// GEMM: 1024 blocks (64 tiles x 16 kp) x 128 threads. Tile 128x64x32.
// 8x8 microtile halves the LDS-pipe floor: LDS bytes = 537M MACs x 4B x
// (1/8+1/8) = 537 MB -> 10.3 us (4x4 was 1.07 GB -> 20.5 us; this WAS the
// hidden ~20us in every 4x4 round). Conflict-free by construction (k-major,
// rows contiguous within a dim — R8's proven property):
//   av: lanes rg=t&15 read rows {4rg..4rg+3} (+64): banks 4rg -> 2-way = free
//   bv: lanes cg=t>>4 (0..3/wave) read cols {4cg..+3} (+32): 4 addrs,
//       16-lane broadcast = free
// Per dim: 4 ds_read_b128 per 64 FMA-instrs. LDS 25.6 KB; no min-waves hint.
// Row stats ride on the A staging registers (thread t owns row t's K-slice).
// out[0] zeroed by block 0 (stream-ordered before epi's atomics).
// ---------------------------------------------------------------------------
__global__ __launch_bounds__(128) void gemm_kernel(
    const float* __restrict__ f, const int* __restrict__ cid,
    float* __restrict__ ws, float* __restrict__ out)
{
    __shared__ float Al[KD * ALP];   // [k][row] 16.9 KB
    __shared__ float Bl[KD * BLP];   // [k][col] 8.7 KB

    const int t     = threadIdx.x;
    const int tile  = blockIdx.x >> 4;
    const int kp    = blockIdx.x & 15;
    const int kbase = kp * KD;
    if (blockIdx.x == 0 && t == 0) out[0] = 0.f;

    // ---- stage A (row = t) + per-row stats for this K-slice ----
    {
        const float* fr = f + (size_t)(tile * BM + t) * DIM + kbase;
        float s = 0.f, q = 0.f;
        #pragma unroll
        for (int j = 0; j < 8; ++j) {
            float4 v = *(const float4*)(fr + 4 * j);
            s += (v.x + v.y) + (v.z + v.w);
            q = fmaf(v.x, v.x, q); q = fmaf(v.y, v.y, q);
            q = fmaf(v.z, v.z, q); q = fmaf(v.w, v.w, q);
            Al[(4*j+0) * ALP + t] = v.x;
            Al[(4*j+1) * ALP + t] = v.y;
            Al[(4*j+2) * ALP + t] = v.z;
            Al[(4*j+3) * ALP + t] = v.w;
        }
        ((float2*)(ws + WS_STAT))[(size_t)kp * NPTS + tile * BM + t] =
            make_float2(s, q);
    }
    // ---- stage B: (col=t&63, half=t>>6) 16 dims each, cid-gather, L2-hot ----
    {
        const int col = t & 63, half = t >> 6;
        const float* gb = f + (size_t)cid[col] * DIM + kbase + half * 16;
        #pragma unroll
        for (int j = 0; j < 16; ++j)
            Bl[(half * 16 + j) * BLP + col] = gb[j];
    }
    __syncthreads();          // the only barrier

    // ---- compute: rows {4rg+i, 64+4rg+i}, cols {4cg+c, 32+4cg+c} ----
    const int rg = t & 15;
    const int cg = t >> 4;    // 0..7 (0..3 within a wave)
    float acc[8][8];
    #pragma unroll
    for (int i = 0; i < 8; ++i)
        #pragma unroll
        for (int c = 0; c < 8; ++c) acc[i][c] = 0.f;

    #pragma unroll 4
    for (int k = 0; k < KD; ++k) {
        const float4 a0 = *(const float4*)&Al[k * ALP + 4 * rg];
        const float4 a1 = *(const float4*)&Al[k * ALP + 64 + 4 * rg];
        const float4 b0 = *(const float4*)&Bl[k * BLP + 4 * cg];
        const float4 b1 = *(const float4*)&Bl[k * BLP + 32 + 4 * cg];
        const float av[8] = {a0.x, a0.y, a0.z, a0.w, a1.x, a1.y, a1.z, a1.w};
        const float bv[8] = {b0.x, b0.y, b0.z, b0.w, b1.x, b1.y, b1.z, b1.w};
        #pragma unroll
        for (int i = 0; i < 8; ++i)
            #pragma unroll
            for (int c = 0; c < 8; ++c)
                acc[i][c] = fmaf(av[i], bv[c], acc[i][c]);
    }

    // ---- store partials [kp*NK+col][pt]: 8 float4 stores, coalesced ----
    const int pbase = tile * BM + 4 * rg;
    #pragma unroll
    for (int c = 0; c < 4; ++c) {
        float* d0 = ws + WS_DOT + (size_t)(kp * NK + 4 * cg + c) * NPTS + pbase;
        *(float4*)(d0)      = make_float4(acc[0][c], acc[1][c], acc[2][c], acc[3][c]);
        *(float4*)(d0 + 64) = make_float4(acc[4][c], acc[5][c], acc[6][c], acc[7][c]);
        float* d1 = ws + WS_DOT + (size_t)(kp * NK + 32 + 4 * cg + c) * NPTS + pbase;
        *(float4*)(d1)      = make_float4(acc[0][4+c], acc[1][4+c], acc[2][4+c], acc[3][4+c]);
        *(float4*)(d1 + 64) = make_float4(acc[4][4+c], acc[5][4+c], acc[6][4+c], acc[7][4+c]);
    }
}

// ---------------------------------------------------------------------------
// Epilogue: 256 blocks x 256 threads (1024 waves). Block owns 32 points;
// thread (p=t&31, g8=t>>5) sums 8 cols x 16 kp partials (coalesced 128B
// segments), packed-key min (first-index tie-break); centroid stats gathered
// from point stats via cid; LDS combine; last-write-wins override; energy
// per-block fp32 atomicAdd (proven R2-R12).
// ---------------------------------------------------------------------------
__global__ __launch_bounds__(256) void epi_kernel(
    const float* __restrict__ ws, const int* __restrict__ cid,
    float* __restrict__ out)
{
    __shared__ u64   keys[8][32];
    __shared__ float cqL[NK], csL[NK];
    __shared__ int   cidL[NK];

    const int t  = threadIdx.x;
    const int p  = t & 31;
    const int g8 = t >> 5;             // 0..7, 8 cols each
    const int gi = blockIdx.x * 32 + p;
    const float2* st = (const float2*)(ws + WS_STAT);

    if (t < NK) {                      // centroid stats = stats of point cid[t]
        const int cr = cid[t];
        float s = 0.f, q = 0.f;
        #pragma unroll
        for (int kp = 0; kp < KP; ++kp) {
            float2 v = st[(size_t)kp * NPTS + cr]; s += v.x; q += v.y;
        }
        cqL[t] = q; csL[t] = s; cidL[t] = cid[t];
    }
    float s = 0.f, q = 0.f;            // this point's stats
    #pragma unroll
    for (int kp = 0; kp < KP; ++kp) {
        float2 v = st[(size_t)kp * NPTS + gi]; s += v.x; q += v.y;
    }
    __syncthreads();

    u64 key = ~0ull;
    #pragma unroll
    for (int c = 0; c < 8; ++c) {
        const int col = g8 * 8 + c;
        float dot = 0.f;
        #pragma unroll
        for (int kp = 0; kp < KP; ++kp)
            dot += ws[WS_DOT + (size_t)(kp * NK + col) * NPTS + gi];
        float d2 = q + cqL[col] - 2.f * dot + 2.0e-6f * (s - csL[col])
                 + 5.12e-10f;
        float dist = sqrtf(fmaxf(d2, 0.f));
        u64 kk = (((u64)__float_as_uint(dist)) << 6) | (unsigned)col;
        key = (kk < key) ? kk : key;
    }
    keys[g8][p] = key;
    __syncthreads();

    if (t < 32) {
        u64 kmin = keys[0][t];
        #pragma unroll
        for (int j = 1; j < 8; ++j) {
            u64 o = keys[j][t];
            kmin = (o < kmin) ? o : kmin;
        }
        const int gp = blockIdx.x * 32 + t;
        float y = (float)(unsigned)(kmin & 63ull);
        for (int k = 0; k < NK; ++k)
            if (cidL[k] == gp) y = (float)k;          // last write wins
        out[1 + gp] = y;
        float e = __uint_as_float((unsigned)(kmin >> 6));
        #pragma unroll
        for (int off = 16; off; off >>= 1) e += __shfl_xor(e, off);
        if (t == 0) atomicAdd(out, -e);
    }
}

extern "C" void kernel_launch(void* const* d_in, const int* in_sizes, int n_in,
                              void* d_out, int out_size, void* d_ws, size_t ws_size,
                              hipStream_t stream) {
    const float* f   = (const float*)d_in[0];
    const int*   cid = (const int*)d_in[1];
    float*       out = (float*)d_out;
    float*       ws  = (float*)d_ws;     // ~34.6 MB used

    gemm_kernel<<<NT * KP, 128, 0, stream>>>(f, cid, ws, out);
    epi_kernel<<<NPTS / 32, 256, 0, stream>>>(ws, cid, out);
}

// Round 17
// 27.306 us; speedup vs baseline: 2.0023x; 2.0023x over previous
//
#include <hip/hip_runtime.h>

typedef unsigned long long u64;

#define NPTS 8192
#define DIM  512
#define NK   64
#define BM   128            // rows per tile
#define KP   8              // K-split parts
#define KD   64             // dims per part
#define NT   (NPTS/BM)      // 64 tiles
#define ALP  132            // Al pitch (floats): 128 rows + 4 pad
#define BLP  68             // Bl pitch (floats): 64 cols + 4 pad

// workspace layout (float offsets)
#define WS_DOT  0                       // [KP*NK][NPTS] = 16.8 MB
#define WS_STAT (KP * NK * NPTS)        // [KP][NPTS] float2 = 512 KB

// ---------------------------------------------------------------------------
// GEMM: 512 blocks = 8 kp (major) x 64 tiles x 256 threads. Tile 128x64x64.
// XCD co-location: blockIdx = kp*64 + tile -> blockIdx mod 8 = tile mod 8
// (64 == 0 mod 8), so ALL 8 kp-partials of a tile are produced on ONE XCD;
// the epi block for that tile (blockIdx = tile) reads them from local L2
// (~2 MB/XCD) instead of an HBM round-trip.
// 8x4 microtile: 3 ds_read_b128 per 32 MACs = 1.5 B/MAC -> 402 MB LDS
// -> ~7.7 us pipe floor (4x4 was 2 B/MAC = 10.3 us). Conflict-free by
// construction (k-major, patterns from R15 which passed):
//   av: rg=t&15 -> rows {4rg..4rg+3} and {64+4rg..}: 16 addrs, 2-way = free
//   bv: cg=t>>4 -> cols {4cg..4cg+3}: 4 addrs/wave, 16-lane bcast = free
// LDS 51.2 KB -> 3 blocks/CU. acc[8][4] ~90 VGPR, NO min-waves hint.
// Stats ride on A staging; out[0] zeroed by block 0 (stream-ordered).
// ---------------------------------------------------------------------------
__global__ __launch_bounds__(256) void gemm_kernel(
    const float* __restrict__ f, const int* __restrict__ cid,
    float* __restrict__ ws, float* __restrict__ out)
{
    __shared__ float Al[KD * ALP];   // [k][row] 33.8 KB
    __shared__ float Bl[KD * BLP];   // [k][col] 17.4 KB

    const int t     = threadIdx.x;
    const int tile  = blockIdx.x & (NT - 1);
    const int kp    = blockIdx.x >> 6;
    const int kbase = kp * KD;
    if (blockIdx.x == 0 && t == 0) out[0] = 0.f;

    // ---- stage A: (srow=t>>1, half=t&1) 32 dims of one row each ----
    {
        const int srow = t >> 1, half = t & 1;
        const float* fr = f + (size_t)(tile * BM + srow) * DIM + kbase + half * 32;
        float s = 0.f, q = 0.f;
        #pragma unroll
        for (int j = 0; j < 8; ++j) {
            float4 v = *(const float4*)(fr + 4 * j);
            s += (v.x + v.y) + (v.z + v.w);
            q = fmaf(v.x, v.x, q); q = fmaf(v.y, v.y, q);
            q = fmaf(v.z, v.z, q); q = fmaf(v.w, v.w, q);
            const int k0 = half * 32 + 4 * j;
            Al[(k0+0) * ALP + srow] = v.x;
            Al[(k0+1) * ALP + srow] = v.y;
            Al[(k0+2) * ALP + srow] = v.z;
            Al[(k0+3) * ALP + srow] = v.w;
        }
        s += __shfl_xor(s, 1);
        q += __shfl_xor(q, 1);
        if (half == 0)
            ((float2*)(ws + WS_STAT))[(size_t)kp * NPTS + tile * BM + srow] =
                make_float2(s, q);
    }
    // ---- stage B: (col=t&63, qg=t>>6) 16 dims each, cid-gather, L2-hot ----
    {
        const int col = t & 63, qg = t >> 6;
        const float* gb = f + (size_t)cid[col] * DIM + kbase + qg * 16;
        #pragma unroll
        for (int j = 0; j < 16; ++j)
            Bl[(qg * 16 + j) * BLP + col] = gb[j];
    }
    __syncthreads();          // the only barrier

    // ---- compute: rows {4rg+i, 64+4rg+i}, cols {4cg..4cg+3} ----
    const int rg = t & 15;
    const int cg = t >> 4;    // 0..15
    float acc[8][4];
    #pragma unroll
    for (int i = 0; i < 8; ++i)
        #pragma unroll
        for (int c = 0; c < 4; ++c) acc[i][c] = 0.f;

    #pragma unroll 4
    for (int k = 0; k < KD; ++k) {
        const float4 a0 = *(const float4*)&Al[k * ALP + 4 * rg];
        const float4 a1 = *(const float4*)&Al[k * ALP + 64 + 4 * rg];
        const float4 b0 = *(const float4*)&Bl[k * BLP + 4 * cg];
        const float av[8] = {a0.x, a0.y, a0.z, a0.w, a1.x, a1.y, a1.z, a1.w};
        #pragma unroll
        for (int i = 0; i < 8; ++i) {
            acc[i][0] = fmaf(av[i], b0.x, acc[i][0]);
            acc[i][1] = fmaf(av[i], b0.y, acc[i][1]);
            acc[i][2] = fmaf(av[i], b0.z, acc[i][2]);
            acc[i][3] = fmaf(av[i], b0.w, acc[i][3]);
        }
    }

    // ---- store partials [kp*NK+col][pt]: float4 x 2 per col, coalesced ----
    const int pbase = tile * BM + 4 * rg;
    #pragma unroll
    for (int c = 0; c < 4; ++c) {
        float* d0 = ws + WS_DOT + (size_t)(kp * NK + 4 * cg + c) * NPTS + pbase;
        *(float4*)(d0)      = make_float4(acc[0][c], acc[1][c], acc[2][c], acc[3][c]);
        *(float4*)(d0 + 64) = make_float4(acc[4][c], acc[5][c], acc[6][c], acc[7][c]);
    }
}

// ---------------------------------------------------------------------------
// Epilogue: 64 blocks (block = tile -> same XCD as its partials) x 512 thr.
// Thread (p=t&127, j=t>>7): j owns cols 16j..16j+15; reads are 256B-coalesced
// rows of [kp*NK+col][pt]. Packed-key min (first-index tie-break), LDS
// combine over 4 j-groups, centroid stats gathered from point stats via cid,
// last-write-wins override, per-wave energy atomics (proven R2-R12).
// ---------------------------------------------------------------------------
__global__ __launch_bounds__(512) void epi_kernel(
    const float* __restrict__ ws, const int* __restrict__ cid,
    float* __restrict__ out)
{
    __shared__ u64   keys[4][BM];
    __shared__ float cqL[NK], csL[NK];
    __shared__ int   cidL[NK];

    const int t    = threadIdx.x;
    const int p    = t & 127;
    const int j    = t >> 7;           // 0..3, 16 cols each
    const int tile = blockIdx.x;
    const int gi   = tile * BM + p;
    const float2* st = (const float2*)(ws + WS_STAT);

    if (t < NK) {                      // centroid stats = stats of point cid[t]
        const int cr = cid[t];
        float s = 0.f, q = 0.f;
        #pragma unroll
        for (int kp = 0; kp < KP; ++kp) {
            float2 v = st[(size_t)kp * NPTS + cr]; s += v.x; q += v.y;
        }
        cqL[t] = q; csL[t] = s; cidL[t] = cid[t];
    }
    float s = 0.f, q = 0.f;            // this point's stats
    #pragma unroll
    for (int kp = 0; kp < KP; ++kp) {
        float2 v = st[(size_t)kp * NPTS + gi]; s += v.x; q += v.y;
    }
    __syncthreads();

    u64 key = ~0ull;
    #pragma unroll 4
    for (int c = 0; c < 16; ++c) {
        const int col = j * 16 + c;
        float dot = 0.f;
        #pragma unroll
        for (int kp = 0; kp < KP; ++kp)
            dot += ws[WS_DOT + (size_t)(kp * NK + col) * NPTS + gi];
        float d2 = q + cqL[col] - 2.f * dot + 2.0e-6f * (s - csL[col])
                 + 5.12e-10f;
        float dist = sqrtf(fmaxf(d2, 0.f));
        u64 kk = (((u64)__float_as_uint(dist)) << 6) | (unsigned)col;
        key = (kk < key) ? kk : key;
    }
    keys[j][p] = key;
    __syncthreads();

    if (t < BM) {                      // threads 0..127 finalize their point
        u64 kmin = keys[0][t];
        #pragma unroll
        for (int g = 1; g < 4; ++g) {
            u64 o = keys[g][t];
            kmin = (o < kmin) ? o : kmin;
        }
        const int gp = tile * BM + t;
        float y = (float)(unsigned)(kmin & 63ull);
        for (int k = 0; k < NK; ++k)
            if (cidL[k] == gp) y = (float)k;          // last write wins
        out[1 + gp] = y;
        float e = __uint_as_float((unsigned)(kmin >> 6));
        #pragma unroll
        for (int off = 32; off; off >>= 1) e += __shfl_xor(e, off);
        if ((t & 63) == 0) atomicAdd(out, -e);
    }
}

extern "C" void kernel_launch(void* const* d_in, const int* in_sizes, int n_in,
                              void* d_out, int out_size, void* d_ws, size_t ws_size,
                              hipStream_t stream) {
    const float* f   = (const float*)d_in[0];
    const int*   cid = (const int*)d_in[1];
    float*       out = (float*)d_out;
    float*       ws  = (float*)d_ws;     // ~17.3 MB used

    gemm_kernel<<<NT * KP, 256, 0, stream>>>(f, cid, ws, out);
    epi_kernel<<<NT, 512, 0, stream>>>(ws, cid, out);
}

// Round 18
// 26.503 us; speedup vs baseline: 2.0629x; 1.0303x over previous
//
#include <hip/hip_runtime.h>

typedef unsigned long long u64;

#define NPTS 8192
#define DIM  512
#define NK   64
#define BM   128            // rows per tile
#define KP   8              // K-split parts
#define KD   64             // dims per part
#define NT   (NPTS/BM)      // 64 tiles
#define ALP  132            // Al pitch (floats): 128 rows + 4 pad
#define BLP  68             // Bl pitch (floats): 64 cols + 4 pad

// workspace layout (float offsets)
#define WS_DOT  0                       // [KP*NK][NPTS] = 16.8 MB
#define WS_STAT (KP * NK * NPTS)        // [KP][NPTS] float2 = 512 KB

// ---------------------------------------------------------------------------
// GEMM: 512 blocks = 8 kp (major) x 64 tiles x 256 threads. Tile 128x64x64.
// Structure frozen from R16 (27.3us, passed): kp-major grid -> all 8 kp-
// partials of a tile on ONE XCD; epi block tile-matched reads local L2.
// 8x4 microtile, k-major LDS, conflict-free patterns (R15/R16 verified).
// R17 deltas (instruction waste only, no structural change):
//   - B-gather via 4x float4 (was 16 scalar loads of the same 64B line)
//   - k-loop unroll 8 (deeper ds_read batching at 2 waves/SIMD)
// ---------------------------------------------------------------------------
__global__ __launch_bounds__(256) void gemm_kernel(
    const float* __restrict__ f, const int* __restrict__ cid,
    float* __restrict__ ws, float* __restrict__ out)
{
    __shared__ float Al[KD * ALP];   // [k][row] 33.8 KB
    __shared__ float Bl[KD * BLP];   // [k][col] 17.4 KB

    const int t     = threadIdx.x;
    const int tile  = blockIdx.x & (NT - 1);
    const int kp    = blockIdx.x >> 6;
    const int kbase = kp * KD;
    if (blockIdx.x == 0 && t == 0) out[0] = 0.f;

    // ---- stage A: (srow=t>>1, half=t&1) 32 dims of one row each ----
    {
        const int srow = t >> 1, half = t & 1;
        const float* fr = f + (size_t)(tile * BM + srow) * DIM + kbase + half * 32;
        float s = 0.f, q = 0.f;
        #pragma unroll
        for (int j = 0; j < 8; ++j) {
            float4 v = *(const float4*)(fr + 4 * j);
            s += (v.x + v.y) + (v.z + v.w);
            q = fmaf(v.x, v.x, q); q = fmaf(v.y, v.y, q);
            q = fmaf(v.z, v.z, q); q = fmaf(v.w, v.w, q);
            const int k0 = half * 32 + 4 * j;
            Al[(k0+0) * ALP + srow] = v.x;
            Al[(k0+1) * ALP + srow] = v.y;
            Al[(k0+2) * ALP + srow] = v.z;
            Al[(k0+3) * ALP + srow] = v.w;
        }
        s += __shfl_xor(s, 1);
        q += __shfl_xor(q, 1);
        if (half == 0)
            ((float2*)(ws + WS_STAT))[(size_t)kp * NPTS + tile * BM + srow] =
                make_float2(s, q);
    }
    // ---- stage B: (col=t&63, qg=t>>6) 16 dims via 4x float4, cid-gather ----
    {
        const int col = t & 63, qg = t >> 6;
        const float* gb = f + (size_t)cid[col] * DIM + kbase + qg * 16;
        #pragma unroll
        for (int j = 0; j < 4; ++j) {
            float4 v = *(const float4*)(gb + 4 * j);
            const int k0 = qg * 16 + 4 * j;
            Bl[(k0+0) * BLP + col] = v.x;
            Bl[(k0+1) * BLP + col] = v.y;
            Bl[(k0+2) * BLP + col] = v.z;
            Bl[(k0+3) * BLP + col] = v.w;
        }
    }
    __syncthreads();          // the only barrier

    // ---- compute: rows {4rg+i, 64+4rg+i}, cols {4cg..4cg+3} ----
    const int rg = t & 15;
    const int cg = t >> 4;    // 0..15
    float acc[8][4];
    #pragma unroll
    for (int i = 0; i < 8; ++i)
        #pragma unroll
        for (int c = 0; c < 4; ++c) acc[i][c] = 0.f;

    #pragma unroll 8
    for (int k = 0; k < KD; ++k) {
        const float4 a0 = *(const float4*)&Al[k * ALP + 4 * rg];
        const float4 a1 = *(const float4*)&Al[k * ALP + 64 + 4 * rg];
        const float4 b0 = *(const float4*)&Bl[k * BLP + 4 * cg];
        const float av[8] = {a0.x, a0.y, a0.z, a0.w, a1.x, a1.y, a1.z, a1.w};
        #pragma unroll
        for (int i = 0; i < 8; ++i) {
            acc[i][0] = fmaf(av[i], b0.x, acc[i][0]);
            acc[i][1] = fmaf(av[i], b0.y, acc[i][1]);
            acc[i][2] = fmaf(av[i], b0.z, acc[i][2]);
            acc[i][3] = fmaf(av[i], b0.w, acc[i][3]);
        }
    }

    // ---- store partials [kp*NK+col][pt]: float4 x 2 per col, coalesced ----
    const int pbase = tile * BM + 4 * rg;
    #pragma unroll
    for (int c = 0; c < 4; ++c) {
        float* d0 = ws + WS_DOT + (size_t)(kp * NK + 4 * cg + c) * NPTS + pbase;
        *(float4*)(d0)      = make_float4(acc[0][c], acc[1][c], acc[2][c], acc[3][c]);
        *(float4*)(d0 + 64) = make_float4(acc[4][c], acc[5][c], acc[6][c], acc[7][c]);
    }
}

// ---------------------------------------------------------------------------
// Epilogue: 64 blocks (block = tile -> same XCD as its partials) x 512 thr.
// Thread (p=t&127, j=t>>7): j owns cols 16j..16j+15; 256B-coalesced reads.
// Packed-key min (first-index tie-break), LDS combine over 4 j-groups,
// centroid stats gathered from point stats via cid, last-write-wins override,
// ONE fp32 atomic per block (energy partials combined through LDS).
// ---------------------------------------------------------------------------
__global__ __launch_bounds__(512) void epi_kernel(
    const float* __restrict__ ws, const int* __restrict__ cid,
    float* __restrict__ out)
{
    __shared__ u64   keys[4][BM];
    __shared__ float cqL[NK], csL[NK];
    __shared__ int   cidL[NK];
    __shared__ float ener[2];

    const int t    = threadIdx.x;
    const int p    = t & 127;
    const int j    = t >> 7;           // 0..3, 16 cols each
    const int tile = blockIdx.x;
    const int gi   = tile * BM + p;
    const float2* st = (const float2*)(ws + WS_STAT);

    if (t < NK) {                      // centroid stats = stats of point cid[t]
        const int cr = cid[t];
        float s = 0.f, q = 0.f;
        #pragma unroll
        for (int kp = 0; kp < KP; ++kp) {
            float2 v = st[(size_t)kp * NPTS + cr]; s += v.x; q += v.y;
        }
        cqL[t] = q; csL[t] = s; cidL[t] = cr;
    }
    float s = 0.f, q = 0.f;            // this point's stats
    #pragma unroll
    for (int kp = 0; kp < KP; ++kp) {
        float2 v = st[(size_t)kp * NPTS + gi]; s += v.x; q += v.y;
    }
    __syncthreads();

    u64 key = ~0ull;
    #pragma unroll 4
    for (int c = 0; c < 16; ++c) {
        const int col = j * 16 + c;
        float dot = 0.f;
        #pragma unroll
        for (int kp = 0; kp < KP; ++kp)
            dot += ws[WS_DOT + (size_t)(kp * NK + col) * NPTS + gi];
        float d2 = q + cqL[col] - 2.f * dot + 2.0e-6f * (s - csL[col])
                 + 5.12e-10f;
        float dist = sqrtf(fmaxf(d2, 0.f));
        u64 kk = (((u64)__float_as_uint(dist)) << 6) | (unsigned)col;
        key = (kk < key) ? kk : key;
    }
    keys[j][p] = key;
    __syncthreads();

    if (t < BM) {                      // threads 0..127 finalize their point
        u64 kmin = keys[0][t];
        #pragma unroll
        for (int g = 1; g < 4; ++g) {
            u64 o = keys[g][t];
            kmin = (o < kmin) ? o : kmin;
        }
        const int gp = tile * BM + t;
        float y = (float)(unsigned)(kmin & 63ull);
        for (int k = 0; k < NK; ++k)
            if (cidL[k] == gp) y = (float)k;          // last write wins
        out[1 + gp] = y;
        float e = __uint_as_float((unsigned)(kmin >> 6));
        #pragma unroll
        for (int off = 32; off; off >>= 1) e += __shfl_xor(e, off);
        if ((t & 63) == 0) ener[t >> 6] = e;
    }
    __syncthreads();
    if (t == 0) atomicAdd(out, -(ener[0] + ener[1]));  // one atomic per block
}

extern "C" void kernel_launch(void* const* d_in, const int* in_sizes, int n_in,
                              void* d_out, int out_size, void* d_ws, size_t ws_size,
                              hipStream_t stream) {
    const float* f   = (const float*)d_in[0];
    const int*   cid = (const int*)d_in[1];
    float*       out = (float*)d_out;
    float*       ws  = (float*)d_ws;     // ~17.3 MB used

    gemm_kernel<<<NT * KP, 256, 0, stream>>>(f, cid, ws, out);
    epi_kernel<<<NT, 512, 0, stream>>>(ws, cid, out);
}